// Round 7
// baseline (139.158 us; speedup 1.0000x reference)
//
#include <hip/hip_runtime.h>
#include <stdint.h>

// BlockAttention fused via augmented Gram matrix. B=8,S=8192,D=H=128,
// BLOCK=256, WINDOW=256 (halo 255; window [n*256-255, n*256+511) clamped).
// No softmax =>
//   out_blk = Q_blk * (scale * Kwin^T Vwin),  K = Wk x + bk etc.
// With xt=[x,1], Wk~=[Wk|bk], Wv~=[Wv|bv]:
//   M^T = Wv~ Gt Wk~^T * scale,  Gt = sum_{s in win} xt_s xt_s^T  (129x129 sym)
// Chunk loop builds ONLY Gt (no per-chunk projections): stage masked xt^T via
// identity-MFMA transpose + packed-pair C-write; 15 symmetric Gram tiles.
// Final: Gt->LDS, P = Wv~ Gt, M^T = P Wk~^T, then q-proj + O as before.
// All LDS leading dims == 2 mod 32 words (68/164/132/36) -> 2-way = free.

#define B_ 8
#define S_ 8192
#define LDT 68     // xT tile LD (shorts); 34 words = 2 mod 32
#define LDG 164    // Gt / P LD (shorts);  82 words = 18 mod 32 (c,c+16 only)
#define LDM 132    // M^T LD (shorts);     66 words = 2 mod 32
#define LDQP 36    // per-wave q patch LD
#define XTB 21760  // bytes per xT buffer: 160*68*2
#define GOFF 43520 // Gt region offset (= 2*XTB)
#define SMEMSZ 96000

using bf16x4 = __attribute__((ext_vector_type(4))) short;
using bf16x8 = __attribute__((ext_vector_type(8))) short;
using f32x16 = __attribute__((ext_vector_type(16))) float;

__device__ __forceinline__ short f2bf(float f) {
  union { float f; uint32_t u; } v; v.f = f;
  uint32_t r = v.u + 0x7fffu + ((v.u >> 16) & 1u);   // RNE
  return (short)(r >> 16);
}

__device__ __forceinline__ bf16x8 cvt8(float4 a, float4 b) {
  bf16x8 r;
  r[0] = f2bf(a.x); r[1] = f2bf(a.y); r[2] = f2bf(a.z); r[3] = f2bf(a.w);
  r[4] = f2bf(b.x); r[5] = f2bf(b.y); r[6] = f2bf(b.z); r[7] = f2bf(b.w);
  return r;
}

__device__ __forceinline__ bf16x8 ld8(const short* p) {   // 8B-aligned LDS read
  bf16x4 lo = *(const bf16x4*)p;
  bf16x4 hi = *(const bf16x4*)(p + 4);
  return __builtin_shufflevector(lo, hi, 0, 1, 2, 3, 4, 5, 6, 7);
}

__global__ __launch_bounds__(512, 2) void fused_kernel(
    const float* __restrict__ x,
    const float* __restrict__ Wq, const float* __restrict__ bq,
    const float* __restrict__ Wk, const float* __restrict__ bk,
    const float* __restrict__ Wv, const float* __restrict__ bv,
    float* __restrict__ out)
{
  // [0,43520): xT dbl buffers; later P (41984) then opat (36864)
  // [43520,96000): Gt (52480); later m_l (33792) + qpat (18432)
  __shared__ __align__(16) char smem[SMEMSZ];

  const int tid  = threadIdx.x;
  const int lane = tid & 63;
  const int wv   = tid >> 6;        // 0..7
  const int c    = lane & 31;
  const int hl   = lane >> 5;

  const int swz = (blockIdx.x & 7) * 32 + (blockIdx.x >> 3);  // XCD swizzle
  const int b   = swz >> 5;
  const int n   = swz & 31;

  const int win_lo = (n == 0) ? 0 : n * 256 - 255;
  const int win_hi = (n == 31) ? S_ : n * 256 + 511;   // exclusive
  const int jlo    = (n == 0) ? 4 : 0;
  const int jhi    = (n == 31) ? 8 : 12;
  const int cbase  = n * 256 - 256;

  const float* xb = x + (size_t)b * S_ * 128;

  // identity B-frags for the transpose MFMA (D = A * I32)
  bf16x8 ib[2];
  #pragma unroll
  for (int kst = 0; kst < 2; ++kst)
    #pragma unroll
    for (int j = 0; j < 8; ++j)
      ib[kst][j] = (kst * 16 + hl * 8 + j == c) ? (short)0x3F80 : (short)0;

  // transpose-stage role: wave handles s-tile st, d-tile dt of each chunk
  const int st = wv >> 2, dt = wv & 3;

  // Gram tile table (upper triangle of 5x5), two tiles per wave (wv7: one)
  int t0i, t0j, t1i, t1j;
  switch (wv) {
    case 0: t0i=0; t0j=0; t1i=0; t1j=4; break;
    case 1: t0i=1; t0j=1; t1i=1; t1j=4; break;
    case 2: t0i=2; t0j=2; t1i=2; t1j=4; break;
    case 3: t0i=3; t0j=3; t1i=3; t1j=4; break;
    case 4: t0i=0; t0j=1; t1i=4; t1j=4; break;
    case 5: t0i=0; t0j=2; t1i=1; t1j=2; break;
    case 6: t0i=0; t0j=3; t1i=1; t1j=3; break;
    default:t0i=2; t0j=3; t1i=2; t1j=3; break;
  }
  const bool two = (wv != 7);

  // zero xT rows 129..159 of both buffers (read by Gram tile-row 4, never
  // written again; row 128 = ones-row is rewritten every chunk)
  {
    int* z0 = (int*)((short*)smem + 129 * LDT);
    int* z1 = (int*)((short*)(smem + XTB) + 129 * LDT);
    for (int i = tid; i < 1054; i += 512) { z0[i] = 0; z1[i] = 0; }
  }

  f32x16 gacc0, gacc1;
  #pragma unroll
  for (int i = 0; i < 16; ++i) { gacc0[i] = 0.f; gacc1[i] = 0.f; }

  // stage one chunk: transpose-MFMA -> masked packed-pair write + ones-row
  auto stageWrite = [&](int c0, short* xt, float4 f0, float4 f1, float4 f2, float4 f3) {
    bf16x8 a0 = cvt8(f0, f1), a1 = cvt8(f2, f3);
    f32x16 cc;
    #pragma unroll
    for (int i = 0; i < 16; ++i) cc[i] = 0.f;
    cc = __builtin_amdgcn_mfma_f32_32x32x16_bf16(a0, ib[0], cc, 0, 0, 0);
    cc = __builtin_amdgcn_mfma_f32_32x32x16_bf16(a1, ib[1], cc, 0, 0, 0);
    const bool mk = (c0 < win_lo) | (c0 + 64 > win_hi);
    short* dst = xt + (dt * 32 + c) * LDT;
    #pragma unroll
    for (int g = 0; g < 4; ++g) {
      #pragma unroll
      for (int p = 0; p < 2; ++p) {
        const int reg = g * 4 + p * 2;
        const int sl  = st * 32 + g * 8 + hl * 4 + p * 2;
        float v0 = cc[reg], v1 = cc[reg + 1];
        if (mk) {
          const int sg = c0 + sl;
          if (sg < win_lo || sg >= win_hi) v0 = 0.f;
          if (sg + 1 < win_lo || sg + 1 >= win_hi) v1 = 0.f;
        }
        const uint32_t pk = (uint32_t)(uint16_t)f2bf(v0) |
                            ((uint32_t)(uint16_t)f2bf(v1) << 16);
        *(uint32_t*)(dst + sl) = pk;
      }
    }
    if (tid < 32) {   // ones-row (row 128) = window mask
      const int s0g = c0 + 2 * tid;
      const uint32_t m0 = (s0g >= win_lo && s0g < win_hi) ? 0x3F80u : 0u;
      const uint32_t m1 = (s0g + 1 >= win_lo && s0g + 1 < win_hi) ? 0x3F80u : 0u;
      *(uint32_t*)(xt + 128 * LDT + 2 * tid) = m0 | (m1 << 16);
    }
  };

  // prologue: stage first chunk into buffer 0
  {
    const float* xr = xb + (size_t)(cbase + jlo * 64 + st * 32 + c) * 128 + dt * 32 + hl * 8;
    float4 f0 = ((const float4*)xr)[0], f1 = ((const float4*)xr)[1];
    float4 f2 = *(const float4*)(xr + 16), f3 = *(const float4*)(xr + 20);
    stageWrite(cbase + jlo * 64, (short*)smem, f0, f1, f2, f3);
  }
  __syncthreads();

  for (int j = jlo; j < jhi; ++j) {
    const int jb = (j - jlo) & 1;
    const short* xcur = (const short*)(smem + (size_t)jb * XTB);
    short* xnxt = (short*)(smem + (size_t)(1 - jb) * XTB);
    const bool more = (j + 1 < jhi);

    float4 f0, f1, f2, f3;
    if (more) {
      const float* xr = xb + (size_t)(cbase + (j + 1) * 64 + st * 32 + c) * 128 + dt * 32 + hl * 8;
      f0 = ((const float4*)xr)[0]; f1 = ((const float4*)xr)[1];
      f2 = *(const float4*)(xr + 16); f3 = *(const float4*)(xr + 20);
    }

    // Gram accumulate on current buffer
    #pragma unroll
    for (int kst = 0; kst < 4; ++kst) {
      const int ko = kst * 16 + hl * 8;
      bf16x8 a0 = ld8(xcur + (t0i * 32 + c) * LDT + ko);
      bf16x8 b0 = ld8(xcur + (t0j * 32 + c) * LDT + ko);
      gacc0 = __builtin_amdgcn_mfma_f32_32x32x16_bf16(a0, b0, gacc0, 0, 0, 0);
      bf16x8 a1 = ld8(xcur + (t1i * 32 + c) * LDT + ko);
      bf16x8 b1 = ld8(xcur + (t1j * 32 + c) * LDT + ko);
      gacc1 = __builtin_amdgcn_mfma_f32_32x32x16_bf16(a1, b1, gacc1, 0, 0, 0);
    }

    if (more) stageWrite(cbase + (j + 1) * 64, xnxt, f0, f1, f2, f3);
    __syncthreads();
  }

  // ---------------- final phase ----------------
  short* gl = (short*)(smem + GOFF);
  const float scale = 0.08838834764831845f;   // 1/sqrt(128), folded into Gt

  // write Gt (scaled, bf16): direct tile + mirrored transpose for ti!=tj
  auto gwrite = [&](f32x16& g, int ti, int tj) {
    #pragma unroll
    for (int reg = 0; reg < 16; ++reg) {
      const int row = ti * 32 + (reg & 3) + 8 * (reg >> 2) + 4 * hl;
      gl[row * LDG + tj * 32 + c] = f2bf(g[reg] * scale);
    }
    if (ti != tj) {
      short* dst = gl + (tj * 32 + c) * LDG + ti * 32;
      #pragma unroll
      for (int g4 = 0; g4 < 4; ++g4) {
        #pragma unroll
        for (int p = 0; p < 2; ++p) {
          const int reg = g4 * 4 + p * 2;
          const int rl  = g4 * 8 + hl * 4 + p * 2;
          const uint32_t pk = (uint32_t)(uint16_t)f2bf(g[reg] * scale) |
                              ((uint32_t)(uint16_t)f2bf(g[reg + 1] * scale) << 16);
          *(uint32_t*)(dst + rl) = pk;
        }
      }
    }
  };
  gwrite(gacc0, t0i, t0j);
  if (two) gwrite(gacc1, t1i, t1j);

  // prefetch this wave's q-row x fragments (global, overlaps barriers)
  bf16x8 aq[8];
  {
    const float* xr = xb + (size_t)(n * 256 + wv * 32 + c) * 128 + hl * 8;
    #pragma unroll
    for (int kst = 0; kst < 8; ++kst) {
      float4 f0 = *(const float4*)(xr + kst * 16);
      float4 f1 = *(const float4*)(xr + kst * 16 + 4);
      aq[kst] = cvt8(f0, f1);
    }
  }
  __syncthreads();   // B1: Gt complete

  // GEMM1: P = Wv~ * Gt  (waves 0-3: ht=wv, d1-tiles 0-2; 4-7: ht=wv-4, 3-4)
  short* pl = (short*)smem;   // P over xT region (dead)
  {
    const int ht = wv & 3;
    const bool lo = (wv < 4);
    const int nd1 = lo ? 3 : 2;
    const int d1b = lo ? 0 : 3;
    const int hr = ht * 32 + c;
    bf16x8 av[9];
    {
      const float* wr = Wv + (size_t)hr * 128 + hl * 8;
      #pragma unroll
      for (int kst = 0; kst < 8; ++kst) {
        float4 f0 = *(const float4*)(wr + kst * 16);
        float4 f1 = *(const float4*)(wr + kst * 16 + 4);
        av[kst] = cvt8(f0, f1);
      }
      bf16x8 a8 = {};
      if (hl == 0) a8[0] = f2bf(bv[hr]);
      av[8] = a8;
    }
    f32x16 pacc[3];
    #pragma unroll
    for (int t = 0; t < 3; ++t)
      #pragma unroll
      for (int i = 0; i < 16; ++i) pacc[t][i] = 0.f;
    #pragma unroll
    for (int t = 0; t < 3; ++t) {
      if (t < nd1) {
        const int d1t = d1b + t;
        #pragma unroll
        for (int kst = 0; kst < 9; ++kst) {
          bf16x8 bb = ld8(gl + (d1t * 32 + c) * LDG + kst * 16 + hl * 8);
          pacc[t] = __builtin_amdgcn_mfma_f32_32x32x16_bf16(av[kst], bb, pacc[t], 0, 0, 0);
        }
      }
    }
    #pragma unroll
    for (int t = 0; t < 3; ++t) {
      if (t < nd1) {
        const int d1t = d1b + t;
        #pragma unroll
        for (int reg = 0; reg < 16; ++reg) {
          const int row = ht * 32 + (reg & 3) + 8 * (reg >> 2) + 4 * hl;
          pl[row * LDG + d1t * 32 + c] = f2bf(pacc[t][reg]);
        }
      }
    }
  }
  __syncthreads();   // B2: P complete (Gt dead)

  // GEMM2: M^T = P * Wk~^T  (wave: ht = wv>>1, d-tiles (wv&1)*2 + {0,1})
  short* m_l = gl;   // M^T over Gt region
  {
    const int ht = wv >> 1;
    const int dt0 = (wv & 1) * 2;
    bf16x8 ap[9];
    {
      const short* pr = pl + (ht * 32 + c) * LDG + hl * 8;
      #pragma unroll
      for (int kst = 0; kst < 9; ++kst) ap[kst] = ld8(pr + kst * 16);
    }
    f32x16 m2[2];
    #pragma unroll
    for (int t = 0; t < 2; ++t)
      #pragma unroll
      for (int i = 0; i < 16; ++i) m2[t][i] = 0.f;
    #pragma unroll
    for (int t = 0; t < 2; ++t) {
      const int dr = (dt0 + t) * 32 + c;
      const float* wr = Wk + (size_t)dr * 128 + hl * 8;
      #pragma unroll
      for (int kst = 0; kst < 8; ++kst) {
        float4 f0 = *(const float4*)(wr + kst * 16);
        float4 f1 = *(const float4*)(wr + kst * 16 + 4);
        bf16x8 bb = cvt8(f0, f1);
        m2[t] = __builtin_amdgcn_mfma_f32_32x32x16_bf16(ap[kst], bb, m2[t], 0, 0, 0);
      }
      bf16x8 b8 = {};
      if (hl == 0) b8[0] = f2bf(bk[dr]);
      m2[t] = __builtin_amdgcn_mfma_f32_32x32x16_bf16(ap[8], b8, m2[t], 0, 0, 0);
    }
    #pragma unroll
    for (int t = 0; t < 2; ++t) {
      #pragma unroll
      for (int reg = 0; reg < 16; ++reg) {
        const int row = ht * 32 + (reg & 3) + 8 * (reg >> 2) + 4 * hl;
        m_l[row * LDM + (dt0 + t) * 32 + c] = f2bf(m2[t][reg]);
      }
    }
  }
  __syncthreads();   // B3: M^T complete (P dead)

  // q-proj + O per wave (32 q-rows), per-d-tile pipeline via wave-local patch
  short* qpat = (short*)(smem + GOFF + 33792) + wv * (32 * LDQP);
  float* opat = (float*)smem + wv * (32 * 36);

  f32x16 oacc[4];
  #pragma unroll
  for (int ht = 0; ht < 4; ++ht)
    #pragma unroll
    for (int i = 0; i < 16; ++i) oacc[ht][i] = 0.f;

  #pragma unroll
  for (int nt = 0; nt < 4; ++nt) {
    bf16x8 wqf[8];
    {
      const float* wr = Wq + (size_t)(nt * 32 + c) * 128 + hl * 8;
      #pragma unroll
      for (int kst = 0; kst < 8; ++kst) {
        float4 f0 = *(const float4*)(wr + kst * 16);
        float4 f1 = *(const float4*)(wr + kst * 16 + 4);
        wqf[kst] = cvt8(f0, f1);
      }
    }
    f32x16 qacc;
    {
      const float bb = bq[nt * 32 + c];
      #pragma unroll
      for (int i = 0; i < 16; ++i) qacc[i] = bb;
    }
    #pragma unroll
    for (int kst = 0; kst < 8; ++kst)
      qacc = __builtin_amdgcn_mfma_f32_32x32x16_bf16(aq[kst], wqf[kst], qacc, 0, 0, 0);
    #pragma unroll
    for (int reg = 0; reg < 16; ++reg) {
      const int row = (reg & 3) + 8 * (reg >> 2) + 4 * hl;
      qpat[row * LDQP + c] = f2bf(qacc[reg]);
    }
    #pragma unroll
    for (int kst2 = 0; kst2 < 2; ++kst2) {
      bf16x8 qf = ld8(qpat + c * LDQP + kst2 * 16 + hl * 8);
      #pragma unroll
      for (int ht = 0; ht < 4; ++ht) {
        bf16x8 bb = ld8(m_l + (ht * 32 + c) * LDM + nt * 32 + kst2 * 16 + hl * 8);
        oacc[ht] = __builtin_amdgcn_mfma_f32_32x32x16_bf16(qf, bb, oacc[ht], 0, 0, 0);
      }
    }
  }

  // epilogue: per-wave f32 patch -> coalesced float4 stores
  float* outb = out + ((size_t)b * S_ + n * 256 + wv * 32) * 128;
  #pragma unroll
  for (int ht = 0; ht < 4; ++ht) {
    #pragma unroll
    for (int reg = 0; reg < 16; ++reg) {
      const int row = (reg & 3) + 8 * (reg >> 2) + 4 * hl;
      opat[row * 36 + c] = oacc[ht][reg];
    }
    #pragma unroll
    for (int p = 0; p < 4; ++p) {
      const int row = p * 8 + (lane >> 3);
      float4 vv = *(const float4*)(opat + row * 36 + (lane & 7) * 4);
      *(float4*)(outb + (size_t)row * 128 + ht * 32 + (lane & 7) * 4) = vv;
    }
  }
}

// ---------------------------------------------------------------------------
extern "C" void kernel_launch(void* const* d_in, const int* in_sizes, int n_in,
                              void* d_out, int out_size, void* d_ws, size_t ws_size,
                              hipStream_t stream) {
  const float* x  = (const float*)d_in[0];
  const float* Wq = (const float*)d_in[1];
  const float* bq = (const float*)d_in[2];
  const float* Wk = (const float*)d_in[3];
  const float* bk = (const float*)d_in[4];
  const float* Wv = (const float*)d_in[5];
  const float* bv = (const float*)d_in[6];
  float* out = (float*)d_out;

  fused_kernel<<<256, 512, 0, stream>>>(x, Wq, bq, Wk, bk, Wv, bv, out);
}